// Round 1
// baseline (455.722 us; speedup 1.0000x reference)
//
#include <hip/hip_runtime.h>
#include <math.h>

#define HIDDEN 256
#define NUM_CLASSES 53
#define NWAVES 4
#define BLOCK (NWAVES * 64)

__global__ __launch_bounds__(BLOCK, 8) void hattn_fused_kernel(
    const float* __restrict__ x,
    const float* __restrict__ rel_emb0,
    const float* __restrict__ rel_emb1,
    const float* __restrict__ disc,
    const float* __restrict__ bias,
    const int* __restrict__ relation_levels,
    const int* __restrict__ label_index,
    const int* __restrict__ scope,
    float* __restrict__ out)
{
    const int bag   = blockIdx.x;
    const int start = scope[bag];
    const int end   = scope[bag + 1];

    const int tid  = threadIdx.x;
    const int lane = tid & 63;
    const int wave = tid >> 6;          // 0..NWAVES-1
    const int col  = lane * 4;          // this lane's 4 hidden columns

    // ---- per-wave online softmax state (per level) ----
    float m0 = -INFINITY, m1 = -INFINITY;
    float l0 = 0.f, l1 = 0.f;
    float4 o0 = make_float4(0.f, 0.f, 0.f, 0.f);
    float4 o1 = make_float4(0.f, 0.f, 0.f, 0.f);

    // ---- main loop: 2-way unrolled over this wave's sentences ----
    for (int s = start + wave; s < end; s += NWAVES * 2) {
        const int s2   = s + NWAVES;
        const bool has2 = (s2 < end);
        const int s2c  = has2 ? s2 : s;   // clamped: load is always valid

        // issue both row loads + index loads up front
        const float4 xa = *reinterpret_cast<const float4*>(x + (size_t)s  * HIDDEN + col);
        const float4 xb = *reinterpret_cast<const float4*>(x + (size_t)s2c * HIDDEN + col);
        const int lbl_a = label_index[s];
        const int lbl_b = label_index[s2c];
        const int ca0 = relation_levels[2 * lbl_a];
        const int ca1 = relation_levels[2 * lbl_a + 1];
        const int cb0 = relation_levels[2 * lbl_b];
        const int cb1 = relation_levels[2 * lbl_b + 1];

        const float4 ra0 = *reinterpret_cast<const float4*>(rel_emb0 + ca0 * HIDDEN + col);
        const float4 ra1 = *reinterpret_cast<const float4*>(rel_emb1 + ca1 * HIDDEN + col);
        const float4 rb0 = *reinterpret_cast<const float4*>(rel_emb0 + cb0 * HIDDEN + col);
        const float4 rb1 = *reinterpret_cast<const float4*>(rel_emb1 + cb1 * HIDDEN + col);

        float pa0 = xa.x * ra0.x + xa.y * ra0.y + xa.z * ra0.z + xa.w * ra0.w;
        float pa1 = xa.x * ra1.x + xa.y * ra1.y + xa.z * ra1.z + xa.w * ra1.w;
        float pb0 = xb.x * rb0.x + xb.y * rb0.y + xb.z * rb0.z + xb.w * rb0.w;
        float pb1 = xb.x * rb1.x + xb.y * rb1.y + xb.z * rb1.z + xb.w * rb1.w;

        // combined wave reduction of 4 partial dots (6 shfl steps)
        #pragma unroll
        for (int off = 32; off > 0; off >>= 1) {
            pa0 += __shfl_xor(pa0, off, 64);
            pa1 += __shfl_xor(pa1, off, 64);
            pb0 += __shfl_xor(pb0, off, 64);
            pb1 += __shfl_xor(pb1, off, 64);
        }

        // ---- level 0 online update ----
        {
            const float mx  = has2 ? fmaxf(pa0, pb0) : pa0;
            const float nm  = fmaxf(m0, mx);
            const float al  = __expf(m0 - nm);          // 0 on first iter (m0=-inf)
            const float ea  = __expf(pa0 - nm);
            const float eb  = has2 ? __expf(pb0 - nm) : 0.f;
            l0 = l0 * al + ea + eb;
            o0.x = o0.x * al + ea * xa.x + eb * xb.x;
            o0.y = o0.y * al + ea * xa.y + eb * xb.y;
            o0.z = o0.z * al + ea * xa.z + eb * xb.z;
            o0.w = o0.w * al + ea * xa.w + eb * xb.w;
            m0 = nm;
        }
        // ---- level 1 online update ----
        {
            const float mx  = has2 ? fmaxf(pa1, pb1) : pa1;
            const float nm  = fmaxf(m1, mx);
            const float al  = __expf(m1 - nm);
            const float ea  = __expf(pa1 - nm);
            const float eb  = has2 ? __expf(pb1 - nm) : 0.f;
            l1 = l1 * al + ea + eb;
            o1.x = o1.x * al + ea * xa.x + eb * xb.x;
            o1.y = o1.y * al + ea * xa.y + eb * xb.y;
            o1.z = o1.z * al + ea * xa.z + eb * xb.z;
            o1.w = o1.w * al + ea * xa.w + eb * xb.w;
            m1 = nm;
        }
    }

    // ---- merge the NWAVES partial states in LDS ----
    __shared__ float s_m[NWAVES][2];
    __shared__ float s_l[NWAVES][2];
    __shared__ float s_o[2][NWAVES][HIDDEN];   // 8 KB
    __shared__ float s_repre[2 * HIDDEN];      // 2 KB

    if (lane == 0) {
        s_m[wave][0] = m0; s_m[wave][1] = m1;
        s_l[wave][0] = l0; s_l[wave][1] = l1;
    }
    *reinterpret_cast<float4*>(&s_o[0][wave][col]) = o0;
    *reinterpret_cast<float4*>(&s_o[1][wave][col]) = o1;
    __syncthreads();

    // thread t handles hidden column t for both levels
    {
        const int t = tid;
        #pragma unroll
        for (int h = 0; h < 2; ++h) {
            float M = -INFINITY;
            #pragma unroll
            for (int w = 0; w < NWAVES; ++w) M = fmaxf(M, s_m[w][h]);
            float L = 0.f, acc = 0.f;
            #pragma unroll
            for (int w = 0; w < NWAVES; ++w) {
                const float mw = s_m[w][h];
                const float f  = (mw == -INFINITY) ? 0.f : __expf(mw - M);
                L   += s_l[w][h] * f;
                acc += s_o[h][w][t] * f;
            }
            const float inv = (L > 0.f) ? (1.f / L) : 0.f;  // empty bag -> 0
            s_repre[h * HIDDEN + t] = acc * inv;
        }
    }
    __syncthreads();

    // ---- epilogue: out[bag][c] = <repre(512), disc[c]> + bias[c] ----
    for (int c = wave; c < NUM_CLASSES; c += NWAVES) {
        const float* dr = disc + c * (2 * HIDDEN);
        float p = 0.f;
        #pragma unroll
        for (int k = 0; k < 8; ++k) {
            const int j = lane + k * 64;          // conflict-free LDS, coalesced disc
            p += s_repre[j] * dr[j];
        }
        #pragma unroll
        for (int off = 32; off > 0; off >>= 1)
            p += __shfl_xor(p, off, 64);
        if (lane == 0)
            out[bag * NUM_CLASSES + c] = p + bias[c];
    }
}

extern "C" void kernel_launch(void* const* d_in, const int* in_sizes, int n_in,
                              void* d_out, int out_size, void* d_ws, size_t ws_size,
                              hipStream_t stream) {
    const float* x               = (const float*)d_in[0];
    const float* rel_emb0        = (const float*)d_in[1];
    const float* rel_emb1        = (const float*)d_in[2];
    const float* disc            = (const float*)d_in[3];
    const float* bias            = (const float*)d_in[4];
    const int*   relation_levels = (const int*)d_in[5];
    const int*   label_index     = (const int*)d_in[6];
    const int*   scope           = (const int*)d_in[7];
    float*       out             = (float*)d_out;

    const int n_bags = in_sizes[7] - 1;   // 4096

    hattn_fused_kernel<<<n_bags, BLOCK, 0, stream>>>(
        x, rel_emb0, rel_emb1, disc, bias, relation_levels, label_index, scope, out);
}

// Round 2
// 430.192 us; speedup vs baseline: 1.0593x; 1.0593x over previous
//
#include <hip/hip_runtime.h>
#include <math.h>

#define HIDDEN 256
#define NUM_CLASSES 53
#define NWAVES 4
#define BLOCK (NWAVES * 64)
#define KP 4   // sentence-pairs per online-update batch

__global__ __launch_bounds__(BLOCK, 4) void hattn_fused_kernel(
    const float* __restrict__ x,
    const float* __restrict__ rel_emb0,
    const float* __restrict__ rel_emb1,
    const float* __restrict__ disc,
    const float* __restrict__ bias,
    const int* __restrict__ relation_levels,
    const int* __restrict__ label_index,
    const int* __restrict__ scope,
    float* __restrict__ out)
{
    const int bag   = blockIdx.x;
    const int start = scope[bag];
    const int end   = scope[bag + 1];

    const int tid  = threadIdx.x;
    const int lane = tid & 63;
    const int wave = tid >> 6;        // 0..3
    const int half = lane >> 5;       // 0: row a, 1: row a+1
    const int j    = lane & 31;       // lane within half
    const int colb = j * 8;           // this lane's 8 hidden columns

    // per-(wave,half) online softmax state, both levels
    float m0 = -INFINITY, l0 = 0.f;
    float m1 = -INFINITY, l1 = 0.f;
    float4 o0a = make_float4(0,0,0,0), o0b = make_float4(0,0,0,0);
    float4 o1a = make_float4(0,0,0,0), o1b = make_float4(0,0,0,0);

    // wave w owns pair-slots {w, w+NW, w+2NW, ...}; batch = KP consecutive slots
    for (int base = start + 2 * wave; base < end; base += 2 * NWAVES * KP) {
        float4 fa[KP], fb[KP];
        int2   rl[KP];
        bool   val[KP];

        #pragma unroll
        for (int k = 0; k < KP; ++k) {
            const int a  = base + 2 * NWAVES * k;
            const int r  = a + half;              // this half's own row
            const bool v = (r < end);
            const int rc = v ? r : start;         // clamped (start<end here)
            val[k] = v;
            const float* xp = x + (size_t)rc * HIDDEN + colb;
            fa[k] = *reinterpret_cast<const float4*>(xp);
            fb[k] = *reinterpret_cast<const float4*>(xp + 4);
            const int lbl = label_index[rc];      // uniform within half -> broadcast
            rl[k] = *reinterpret_cast<const int2*>(relation_levels + 2 * lbl);
        }

        float lg0[KP], lg1[KP];
        #pragma unroll
        for (int k = 0; k < KP; ++k) {
            const float* p0 = rel_emb0 + (size_t)rl[k].x * HIDDEN + colb;
            const float* p1 = rel_emb1 + (size_t)rl[k].y * HIDDEN + colb;
            const float4 r0a = *reinterpret_cast<const float4*>(p0);
            const float4 r0b = *reinterpret_cast<const float4*>(p0 + 4);
            const float4 r1a = *reinterpret_cast<const float4*>(p1);
            const float4 r1b = *reinterpret_cast<const float4*>(p1 + 4);

            float pa0 = fa[k].x*r0a.x + fa[k].y*r0a.y + fa[k].z*r0a.z + fa[k].w*r0a.w
                      + fb[k].x*r0b.x + fb[k].y*r0b.y + fb[k].z*r0b.z + fb[k].w*r0b.w;
            float pa1 = fa[k].x*r1a.x + fa[k].y*r1a.y + fa[k].z*r1a.z + fa[k].w*r1a.w
                      + fb[k].x*r1b.x + fb[k].y*r1b.y + fb[k].z*r1b.z + fb[k].w*r1b.w;

            // 32-lane reduce (offsets <=16 never cross the half boundary)
            #pragma unroll
            for (int off = 16; off > 0; off >>= 1) {
                pa0 += __shfl_xor(pa0, off, 64);
                pa1 += __shfl_xor(pa1, off, 64);
            }
            lg0[k] = val[k] ? pa0 : -INFINITY;
            lg1[k] = val[k] ? pa1 : -INFINITY;
        }

        // ---- one online update per batch: level 0 ----
        {
            float bm = fmaxf(fmaxf(lg0[0], lg0[1]), fmaxf(lg0[2], lg0[3]));
            const float nm = fmaxf(m0, bm);
            const float al = (m0 == -INFINITY) ? 0.f : __expf(m0 - nm);
            float e[KP], se = 0.f;
            #pragma unroll
            for (int k = 0; k < KP; ++k) {
                e[k] = (lg0[k] == -INFINITY) ? 0.f : __expf(lg0[k] - nm);
                se += e[k];
            }
            l0 = l0 * al + se;
            o0a.x = o0a.x*al + e[0]*fa[0].x + e[1]*fa[1].x + e[2]*fa[2].x + e[3]*fa[3].x;
            o0a.y = o0a.y*al + e[0]*fa[0].y + e[1]*fa[1].y + e[2]*fa[2].y + e[3]*fa[3].y;
            o0a.z = o0a.z*al + e[0]*fa[0].z + e[1]*fa[1].z + e[2]*fa[2].z + e[3]*fa[3].z;
            o0a.w = o0a.w*al + e[0]*fa[0].w + e[1]*fa[1].w + e[2]*fa[2].w + e[3]*fa[3].w;
            o0b.x = o0b.x*al + e[0]*fb[0].x + e[1]*fb[1].x + e[2]*fb[2].x + e[3]*fb[3].x;
            o0b.y = o0b.y*al + e[0]*fb[0].y + e[1]*fb[1].y + e[2]*fb[2].y + e[3]*fb[3].y;
            o0b.z = o0b.z*al + e[0]*fb[0].z + e[1]*fb[1].z + e[2]*fb[2].z + e[3]*fb[3].z;
            o0b.w = o0b.w*al + e[0]*fb[0].w + e[1]*fb[1].w + e[2]*fb[2].w + e[3]*fb[3].w;
            m0 = nm;
        }
        // ---- level 1 ----
        {
            float bm = fmaxf(fmaxf(lg1[0], lg1[1]), fmaxf(lg1[2], lg1[3]));
            const float nm = fmaxf(m1, bm);
            const float al = (m1 == -INFINITY) ? 0.f : __expf(m1 - nm);
            float e[KP], se = 0.f;
            #pragma unroll
            for (int k = 0; k < KP; ++k) {
                e[k] = (lg1[k] == -INFINITY) ? 0.f : __expf(lg1[k] - nm);
                se += e[k];
            }
            l1 = l1 * al + se;
            o1a.x = o1a.x*al + e[0]*fa[0].x + e[1]*fa[1].x + e[2]*fa[2].x + e[3]*fa[3].x;
            o1a.y = o1a.y*al + e[0]*fa[0].y + e[1]*fa[1].y + e[2]*fa[2].y + e[3]*fa[3].y;
            o1a.z = o1a.z*al + e[0]*fa[0].z + e[1]*fa[1].z + e[2]*fa[2].z + e[3]*fa[3].z;
            o1a.w = o1a.w*al + e[0]*fa[0].w + e[1]*fa[1].w + e[2]*fa[2].w + e[3]*fa[3].w;
            o1b.x = o1b.x*al + e[0]*fb[0].x + e[1]*fb[1].x + e[2]*fb[2].x + e[3]*fb[3].x;
            o1b.y = o1b.y*al + e[0]*fb[0].y + e[1]*fb[1].y + e[2]*fb[2].y + e[3]*fb[3].y;
            o1b.z = o1b.z*al + e[0]*fb[0].z + e[1]*fb[1].z + e[2]*fb[2].z + e[3]*fb[3].z;
            o1b.w = o1b.w*al + e[0]*fb[0].w + e[1]*fb[1].w + e[2]*fb[2].w + e[3]*fb[3].w;
            m1 = nm;
        }
    }

    // ---- merge the 8 (wave,half) partial states via LDS ----
    __shared__ float s_m[NWAVES][2][2];           // [wave][half][lvl]
    __shared__ float s_l[NWAVES][2][2];
    __shared__ float s_o[2][NWAVES][2][HIDDEN];   // 16 KB
    __shared__ float s_repre[2 * HIDDEN];         // 2 KB

    if (j == 0) {
        s_m[wave][half][0] = m0;  s_m[wave][half][1] = m1;
        s_l[wave][half][0] = l0;  s_l[wave][half][1] = l1;
    }
    {
        float4* d0 = reinterpret_cast<float4*>(&s_o[0][wave][half][colb]);
        d0[0] = o0a; d0[1] = o0b;
        float4* d1 = reinterpret_cast<float4*>(&s_o[1][wave][half][colb]);
        d1[0] = o1a; d1[1] = o1b;
    }
    __syncthreads();

    {
        const int t = tid;   // hidden column
        #pragma unroll
        for (int h = 0; h < 2; ++h) {
            float M = -INFINITY;
            #pragma unroll
            for (int w = 0; w < NWAVES; ++w)
                #pragma unroll
                for (int hh = 0; hh < 2; ++hh)
                    M = fmaxf(M, s_m[w][hh][h]);
            float L = 0.f, acc = 0.f;
            #pragma unroll
            for (int w = 0; w < NWAVES; ++w)
                #pragma unroll
                for (int hh = 0; hh < 2; ++hh) {
                    const float mw = s_m[w][hh][h];
                    const float f  = (mw == -INFINITY) ? 0.f : __expf(mw - M);
                    L   += s_l[w][hh][h] * f;
                    acc += s_o[h][w][hh][t] * f;
                }
            s_repre[h * HIDDEN + t] = (L > 0.f) ? (acc / L) : 0.f;
        }
    }
    __syncthreads();

    // ---- epilogue: out[bag][c] = <repre(512), disc[c]> + bias[c] ----
    for (int c = wave; c < NUM_CLASSES; c += NWAVES) {
        const float* dr = disc + c * (2 * HIDDEN);
        float p = 0.f;
        #pragma unroll
        for (int k = 0; k < 8; ++k) {
            const int idx = lane + k * 64;
            p += s_repre[idx] * dr[idx];
        }
        #pragma unroll
        for (int off = 32; off > 0; off >>= 1)
            p += __shfl_xor(p, off, 64);
        if (lane == 0)
            out[bag * NUM_CLASSES + c] = p + bias[c];
    }
}

extern "C" void kernel_launch(void* const* d_in, const int* in_sizes, int n_in,
                              void* d_out, int out_size, void* d_ws, size_t ws_size,
                              hipStream_t stream) {
    const float* x               = (const float*)d_in[0];
    const float* rel_emb0        = (const float*)d_in[1];
    const float* rel_emb1        = (const float*)d_in[2];
    const float* disc            = (const float*)d_in[3];
    const float* bias            = (const float*)d_in[4];
    const int*   relation_levels = (const int*)d_in[5];
    const int*   label_index     = (const int*)d_in[6];
    const int*   scope           = (const int*)d_in[7];
    float*       out             = (float*)d_out;

    const int n_bags = in_sizes[7] - 1;   // 4096

    hattn_fused_kernel<<<n_bags, BLOCK, 0, stream>>>(
        x, rel_emb0, rel_emb1, disc, bias, relation_levels, label_index, scope, out);
}